// Round 1
// baseline (320.483 us; speedup 1.0000x reference)
//
#include <hip/hip_runtime.h>
#include <hip/hip_bf16.h>
#include <cstddef>

// Problem geometry (fixed by reference):
//   x: (8, 64, 128, 128) fp32 | w1: (64,64,1,1) | b1: (64,)
//   w2: (9,64,5,5) | tc1: (16,64,1,1) | tc2: (64,16,1,1)
//   out: (8, 64, 128, 128) fp32
// Fusion: wt = conv5x5(conv1x1(x)+b1) == conv5x5_eff(x) + in-bounds-gated beta
//   W_eff[ci][t][k] = sum_c w2[k][c][t] * w1[c][ci]   (t = eh*5+ew)
//   beta[t][k]      = sum_c w2[k][c][t] * b1[c]

#define B 8
#define C 64
#define HW 128
#define NK 9           // K*K
#define NT 25          // EK*EK

// ---------------- kernel 1: per-channel mean of x ----------------
__global__ __launch_bounds__(256) void xcon_kernel(const float* __restrict__ x,
                                                   float* __restrict__ xcon) {
    const int c = blockIdx.x;
    float s = 0.f;
    for (int b = 0; b < B; ++b) {
        const float4* p = (const float4*)(x + ((size_t)(b * C + c)) * (HW * HW));
        for (int idx = threadIdx.x; idx < (HW * HW) / 4; idx += 256) {
            float4 v = p[idx];
            s += (v.x + v.y) + (v.z + v.w);
        }
    }
    __shared__ float red[256];
    red[threadIdx.x] = s;
    __syncthreads();
    for (int off = 128; off > 0; off >>= 1) {
        if (threadIdx.x < off) red[threadIdx.x] += red[threadIdx.x + off];
        __syncthreads();
    }
    if (threadIdx.x == 0) xcon[c] = red[0] * (1.f / (B * HW * HW));
}

// ---------------- kernel 2: consensus vector tmp[64] ----------------
__global__ __launch_bounds__(64) void tmp_kernel(const float* __restrict__ xcon,
                                                 const float* __restrict__ tc1,
                                                 const float* __restrict__ tc2,
                                                 float* __restrict__ tmp) {
    __shared__ float xc[C], h1[16];
    const int t = threadIdx.x;
    xc[t] = xcon[t];
    __syncthreads();
    if (t < 16) {
        float s = 0.f;
        for (int c = 0; c < C; ++c) s += tc1[t * C + c] * xc[c];
        h1[t] = fmaxf(s, 0.f);
    }
    __syncthreads();
    float s = 0.f;
    for (int o = 0; o < 16; ++o) s += tc2[t * 16 + o] * h1[o];
    tmp[t] = fmaxf(s, 0.f);
}

// ---------------- kernel 3: effective conv weights ----------------
__global__ __launch_bounds__(256) void weff_kernel(const float* __restrict__ w1,
                                                   const float* __restrict__ b1,
                                                   const float* __restrict__ w2,
                                                   float* __restrict__ Weff,
                                                   float* __restrict__ beta) {
    const int idx = blockIdx.x * 256 + threadIdx.x;
    if (idx < C * NT * NK) {                 // 14400 W_eff entries
        const int ci = idx / (NT * NK);
        const int r = idx - ci * (NT * NK);
        const int t = r / NK;
        const int k = r - t * NK;
        float s = 0.f;
        for (int c = 0; c < C; ++c)
            s += w2[(k * C + c) * NT + t] * w1[c * C + ci];
        Weff[(ci * NT + t) * NK + k] = s;
    } else if (idx < C * NT * NK + NT * NK) { // 225 beta entries
        const int r = idx - C * NT * NK;
        const int t = r / NK;
        const int k = r - t * NK;
        float s = 0.f;
        for (int c = 0; c < C; ++c)
            s += w2[(k * C + c) * NT + t] * b1[c];
        beta[t * NK + k] = s;
    }
}

// ---------------- kernel 4: fused 5x5 conv -> wt (8,9,128,128) ----------------
// block: 256 threads = 16x16 pixel tile; grid: (64 tiles, 8 batch)
// LDS: 16 channels x 20x20 halo tile = 25.6 KB; W_eff read with wave-uniform
// indices (scalar loads).
__global__ __launch_bounds__(256) void conv_kernel(const float* __restrict__ x,
                                                   const float* __restrict__ Weff,
                                                   const float* __restrict__ beta,
                                                   float* __restrict__ wt) {
    __shared__ float lx[16 * 20 * 20];
    const int b = blockIdx.y;
    const int ty = blockIdx.x >> 3, tx = blockIdx.x & 7;
    const int i0 = ty * 16, j0 = tx * 16;
    const int ti = threadIdx.x >> 4, tj = threadIdx.x & 15;
    const int i = i0 + ti, j = j0 + tj;

    float acc[NK];
#pragma unroll
    for (int k = 0; k < NK; ++k) acc[k] = 0.f;

    for (int c0 = 0; c0 < C; c0 += 16) {
        __syncthreads();
        for (int idx = threadIdx.x; idx < 16 * 400; idx += 256) {
            const int ci = idx / 400;
            const int r = idx - ci * 400;
            const int li = r / 20, lj = r - li * 20;
            const int gi = i0 + li - 2, gj = j0 + lj - 2;
            float v = 0.f;   // zero padding (pads y==0 for the 5x5 conv)
            if (gi >= 0 && gi < HW && gj >= 0 && gj < HW)
                v = x[(((size_t)b * C + c0 + ci) * HW + gi) * HW + gj];
            lx[idx] = v;
        }
        __syncthreads();
        for (int ci = 0; ci < 16; ++ci) {
            const float* wrow = Weff + (size_t)(c0 + ci) * NT * NK;
#pragma unroll
            for (int t = 0; t < NT; ++t) {
                const int dh = t / 5, dw = t - dh * 5;
                const float xv = lx[ci * 400 + (ti + dh) * 20 + (tj + dw)];
#pragma unroll
                for (int k = 0; k < NK; ++k)
                    acc[k] += wrow[t * NK + k] * xv;
            }
        }
    }
    // bias contribution: only taps that land in-bounds (conv zero-pads y)
#pragma unroll
    for (int t = 0; t < NT; ++t) {
        const int dh = t / 5 - 2, dw = t - (t / 5) * 5 - 2;
        const int gi = i + dh, gj = j + dw;
        if (gi >= 0 && gi < HW && gj >= 0 && gj < HW) {
#pragma unroll
            for (int k = 0; k < NK; ++k) acc[k] += beta[t * NK + k];
        }
    }
#pragma unroll
    for (int k = 0; k < NK; ++k)
        wt[(((size_t)b * NK + k) * HW + i) * HW + j] = acc[k];
}

// ---------------- kernel 5: softmax over 9 taps + dynamic blur ----------------
// block: 256 threads = 16x16 pixel tile; loop over 64 channels, staging an
// 18x18 reflect-padded x tile per channel in LDS.
__global__ __launch_bounds__(256) void out_kernel(const float* __restrict__ x,
                                                  const float* __restrict__ wt,
                                                  const float* __restrict__ tmp,
                                                  float* __restrict__ out) {
    __shared__ float lt[C];
    __shared__ float lx[18 * 18];
    const int b = blockIdx.y;
    const int ty = blockIdx.x >> 3, tx = blockIdx.x & 7;
    const int i0 = ty * 16, j0 = tx * 16;
    const int ti = threadIdx.x >> 4, tj = threadIdx.x & 15;
    const int i = i0 + ti, j = j0 + tj;

    if (threadIdx.x < C) lt[threadIdx.x] = tmp[threadIdx.x];

    float w[NK];
#pragma unroll
    for (int k = 0; k < NK; ++k)
        w[k] = wt[(((size_t)b * NK + k) * HW + i) * HW + j];

    for (int c = 0; c < C; ++c) {
        __syncthreads();   // also covers lt on first iteration
        for (int idx = threadIdx.x; idx < 18 * 18; idx += 256) {
            const int li = idx / 18, lj = idx - li * 18;
            int gi = i0 + li - 1, gj = j0 + lj - 1;
            gi = gi < 0 ? -gi : (gi > HW - 1 ? 2 * (HW - 1) - gi : gi);
            gj = gj < 0 ? -gj : (gj > HW - 1 ? 2 * (HW - 1) - gj : gj);
            lx[idx] = x[(((size_t)b * C + c) * HW + gi) * HW + gj];
        }
        __syncthreads();
        const float t = lt[c];
        float l[NK], m = -1e30f;
#pragma unroll
        for (int k = 0; k < NK; ++k) {
            l[k] = w[k] * t;
            m = fmaxf(m, l[k]);
        }
        float e[NK], s = 0.f;
#pragma unroll
        for (int k = 0; k < NK; ++k) {
            e[k] = __expf(l[k] - m);
            s += e[k];
        }
        float o = 0.f;
#pragma unroll
        for (int k = 0; k < NK; ++k) {
            const int dh = k / 3, dw = k - dh * 3;
            o += e[k] * lx[(ti + dh) * 18 + (tj + dw)];
        }
        out[(((size_t)b * C + c) * HW + i) * HW + j] = o / s;
    }
}

extern "C" void kernel_launch(void* const* d_in, const int* in_sizes, int n_in,
                              void* d_out, int out_size, void* d_ws, size_t ws_size,
                              hipStream_t stream) {
    const float* x   = (const float*)d_in[0];
    const float* w1  = (const float*)d_in[1];
    const float* b1  = (const float*)d_in[2];
    const float* w2  = (const float*)d_in[3];
    const float* tc1 = (const float*)d_in[4];
    const float* tc2 = (const float*)d_in[5];
    float* out = (float*)d_out;

    // workspace layout (floats)
    float* ws   = (float*)d_ws;
    float* xcon = ws;                 // 64
    float* tmp  = ws + 64;            // 64
    float* Weff = ws + 128;           // 14400
    float* beta = ws + 128 + 14400;   // 225
    float* wt   = ws + 14848;         // 8*9*128*128 = 1179648

    xcon_kernel<<<C, 256, 0, stream>>>(x, xcon);
    tmp_kernel<<<1, 64, 0, stream>>>(xcon, tc1, tc2, tmp);
    weff_kernel<<<(C * NT * NK + NT * NK + 255) / 256, 256, 0, stream>>>(w1, b1, w2, Weff, beta);
    conv_kernel<<<dim3(64, B), 256, 0, stream>>>(x, Weff, beta, wt);
    out_kernel<<<dim3(64, B), 256, 0, stream>>>(x, wt, tmp, out);
}

// Round 2
// 173.914 us; speedup vs baseline: 1.8428x; 1.8428x over previous
//
#include <hip/hip_runtime.h>
#include <hip/hip_bf16.h>
#include <cstddef>

// x: (8,64,128,128) fp32 | w1:(64,64,1,1) | b1:(64,) | w2:(9,64,5,5)
// tc1:(16,64,1,1) | tc2:(64,16,1,1) | out:(8,64,128,128) fp32
//
// wt = conv5x5(conv1x1(x)+b1)  ==  GEMM:  wt[k,n] = sum_{kappa=(t,c)} A[k,kappa]*B[kappa,n]
//   A[k,(t,c)] = Weff[c][t][k] = sum_cc w2[k,cc,t]*w1[cc,c]   (split hi/lo bf16)
//   B[(t,c),n] = bf16(x[c, pix_n + off(t)])  (zero outside image = y zero-pad)
// + border-gated bias betaG (beta[t][k]=sum_cc w2[k,cc,t]*b1[cc], gated by y in-bounds)

#define B 8
#define C 64
#define HW 128
#define NK 9
#define NT 25

typedef __attribute__((ext_vector_type(8))) short short8;    // 8 bf16 (4 VGPRs)
typedef __attribute__((ext_vector_type(4))) float float4v;   // 4 fp32 acc

__device__ __forceinline__ unsigned short f2bf(float f) {
    unsigned int u = __float_as_uint(f);
    unsigned int r = u + 0x7FFF + ((u >> 16) & 1);   // RNE
    return (unsigned short)(r >> 16);
}

// ---------- kernel 1: x (b,c,h,w) fp32 -> xT (b,h,w,c) bf16 ----------
// grid (128 gi, 8 b), block 256. LDS tile 64c x 128gj, stride 129 (conflict-free).
__global__ __launch_bounds__(256) void transpose_kernel(const float* __restrict__ x,
                                                        unsigned short* __restrict__ xT) {
    __shared__ float tile[64 * 129];
    const int gi = blockIdx.x, b = blockIdx.y;
    // read: 64 c x 32 float4
    for (int it = 0; it < 8; ++it) {
        const int idx = it * 256 + threadIdx.x;
        const int cidx = idx >> 5, f4 = idx & 31;
        float4 v = *(const float4*)(x + (((size_t)(b * C + cidx)) * HW + gi) * HW + f4 * 4);
        tile[cidx * 129 + f4 * 4 + 0] = v.x;
        tile[cidx * 129 + f4 * 4 + 1] = v.y;
        tile[cidx * 129 + f4 * 4 + 2] = v.z;
        tile[cidx * 129 + f4 * 4 + 3] = v.w;
    }
    __syncthreads();
    // write: 128 gj x 8 c-octets, each lane packs 8 channels -> 16B
    for (int it = 0; it < 4; ++it) {
        const int idx = it * 256 + threadIdx.x;
        const int gj = idx >> 3, c8 = idx & 7;
        unsigned int p[4];
#pragma unroll
        for (int s = 0; s < 4; ++s) {
            unsigned int lo = f2bf(tile[(c8 * 8 + 2 * s) * 129 + gj]);
            unsigned int hi = f2bf(tile[(c8 * 8 + 2 * s + 1) * 129 + gj]);
            p[s] = lo | (hi << 16);
        }
        uint4 outv = {p[0], p[1], p[2], p[3]};
        *(uint4*)(xT + (((size_t)b * (HW * HW) + gi * HW + gj) * C + c8 * 8)) = outv;
    }
}

// ---------- kernel 2: partial channel means ----------
// grid 256: block (c, qb): qb handles batches {2qb, 2qb+1}
__global__ __launch_bounds__(256) void xcon_part_kernel(const float* __restrict__ x,
                                                        float* __restrict__ part) {
    const int c = blockIdx.x >> 2, qb = blockIdx.x & 3;
    float s = 0.f;
    for (int bb = 0; bb < 2; ++bb) {
        const int b = qb * 2 + bb;
        const float4* p = (const float4*)(x + ((size_t)(b * C + c)) * (HW * HW));
        for (int idx = threadIdx.x; idx < (HW * HW) / 4; idx += 256) {
            float4 v = p[idx];
            s += (v.x + v.y) + (v.z + v.w);
        }
    }
    __shared__ float red[256];
    red[threadIdx.x] = s;
    __syncthreads();
    for (int off = 128; off > 0; off >>= 1) {
        if (threadIdx.x < off) red[threadIdx.x] += red[threadIdx.x + off];
        __syncthreads();
    }
    if (threadIdx.x == 0) part[c * 4 + qb] = red[0];
}

// ---------- kernel 3: consensus vector tmp[64] ----------
__global__ __launch_bounds__(64) void tmp_kernel(const float* __restrict__ part,
                                                 const float* __restrict__ tc1,
                                                 const float* __restrict__ tc2,
                                                 float* __restrict__ tmp) {
    __shared__ float xc[C], h1[16];
    const int t = threadIdx.x;
    xc[t] = (part[t * 4 + 0] + part[t * 4 + 1] + part[t * 4 + 2] + part[t * 4 + 3])
            * (1.f / (B * HW * HW));
    __syncthreads();
    if (t < 16) {
        float s = 0.f;
        for (int c = 0; c < C; ++c) s += tc1[t * C + c] * xc[c];
        h1[t] = fmaxf(s, 0.f);
    }
    __syncthreads();
    float s = 0.f;
    for (int o = 0; o < 16; ++o) s += tc2[t * 16 + o] * h1[o];
    tmp[t] = fmaxf(s, 0.f);
}

// ---------- kernel 4: prepacked MFMA A-fragments (hi/lo bf16) ----------
// Abuf layout: [chunk=t*2+ch][pass hi/lo][512] ushorts, slot = (quad*16+m)*8+j
// value = Weff[c = ch*32+quad*8+j][t][k=m], zero for m>=9.
__global__ __launch_bounds__(256) void weffA_kernel(const float* __restrict__ w1,
                                                    const float* __restrict__ w2,
                                                    unsigned short* __restrict__ Abuf) {
    const int idx = blockIdx.x * 256 + threadIdx.x;   // 25600 slots
    if (idx >= 50 * 512) return;
    const int chunk = idx >> 9;            // t*2+ch
    const int rem = idx & 511;             // (quad*16+m)*8+j
    const int quad = rem >> 7;
    const int m = (rem >> 3) & 15;
    const int j = rem & 7;
    const int t = chunk >> 1, ch = chunk & 1;
    const int c = ch * 32 + quad * 8 + j;
    unsigned short hi = 0, lo = 0;
    if (m < NK) {
        float s = 0.f;
        for (int cc = 0; cc < C; ++cc)
            s += w2[(m * C + cc) * NT + t] * w1[cc * C + c];
        hi = f2bf(s);
        float fhi = __uint_as_float(((unsigned int)hi) << 16);
        lo = f2bf(s - fhi);
    }
    Abuf[chunk * 1024 + rem] = hi;
    Abuf[chunk * 1024 + 512 + rem] = lo;
}

// ---------- kernel 5: beta + border-gated betaG table ----------
// betaG[ic][jc][k] = sum over taps whose y-sample is in-bounds for border class
__global__ __launch_bounds__(256) void beta_kernel(const float* __restrict__ b1,
                                                   const float* __restrict__ w2,
                                                   float* __restrict__ betaG) {
    __shared__ float beta_s[NT * NK];
    const int t0 = threadIdx.x;
    if (t0 < NT * NK) {
        const int t = t0 / NK, k = t0 - t * NK;
        float s = 0.f;
        for (int cc = 0; cc < C; ++cc)
            s += w2[(k * C + cc) * NT + t] * b1[cc];
        beta_s[t0] = s;
    }
    __syncthreads();
    if (t0 < 225) {   // (ic,jc,k)
        const int ic = t0 / 45, jc = (t0 / 9) % 5, k = t0 % 9;
        // class: 0 -> gi==0 (eh>=2), 1 -> gi==1 (eh>=1), 2 interior, 3 -> 126 (eh<=3), 4 -> 127 (eh<=2)
        float s = 0.f;
        for (int eh = 0; eh < 5; ++eh) {
            bool rok = (ic == 0) ? (eh >= 2) : (ic == 1) ? (eh >= 1)
                      : (ic == 3) ? (eh <= 3) : (ic == 4) ? (eh <= 2) : true;
            if (!rok) continue;
            for (int ew = 0; ew < 5; ++ew) {
                bool cok = (jc == 0) ? (ew >= 2) : (jc == 1) ? (ew >= 1)
                          : (jc == 3) ? (ew <= 3) : (jc == 4) ? (ew <= 2) : true;
                if (cok) s += beta_s[(eh * 5 + ew) * NK + k];
            }
        }
        betaG[t0] = s;
    }
}

// ---------- kernel 6: MFMA conv -> wt (8,9,128,128) ----------
// block 256 = 4 waves; 16x16 pixel tile; stage 20x20x32c bf16 (25.6KB), 2 c-halves.
// Wave w owns rows w*4..w*4+3 (4 N-subtiles of 16 pixels each).
__global__ __launch_bounds__(256) void conv_mfma_kernel(const unsigned short* __restrict__ xT,
                                                        const unsigned short* __restrict__ Abuf,
                                                        const float* __restrict__ betaG,
                                                        float* __restrict__ wt) {
    __shared__ unsigned short stag[400 * 32];   // [pix 20x20][c 32]
    __shared__ float bg[225];
    const int b = blockIdx.y;
    const int ty = blockIdx.x >> 3, tx = blockIdx.x & 7;
    const int i0 = ty * 16, j0 = tx * 16;
    const int lane = threadIdx.x & 63, wid = threadIdx.x >> 6;
    const int n = lane & 15, q = lane >> 4;
    const int lane_off = n * 32 + q * 8;        // ushort offset within pixel-row group

    if (threadIdx.x < 225) bg[threadIdx.x] = betaG[threadIdx.x];

    float4v acc[4];
    const float4v zero4 = {0.f, 0.f, 0.f, 0.f};
#pragma unroll
    for (int g = 0; g < 4; ++g) acc[g] = zero4;

    for (int ch = 0; ch < 2; ++ch) {
        __syncthreads();
        // stage: 400 pixels x 32 channels (16B per lane-task)
        for (int idx = threadIdx.x; idx < 1600; idx += 256) {
            const int pix = idx >> 2, part = idx & 3;
            const int li = pix / 20, lj = pix - li * 20;
            const int gi = i0 + li - 2, gj = j0 + lj - 2;
            uint4 v = {0u, 0u, 0u, 0u};
            if (gi >= 0 && gi < HW && gj >= 0 && gj < HW)
                v = *(const uint4*)(xT + (((size_t)b * (HW * HW) + gi * HW + gj) * C
                                          + ch * 32 + part * 8));
            *(uint4*)(stag + pix * 32 + part * 8) = v;
        }
        __syncthreads();
        const unsigned short* Abase = Abuf + ch * 1024 + lane * 8;
#pragma unroll
        for (int eh = 0; eh < 5; ++eh) {
#pragma unroll
            for (int ew = 0; ew < 5; ++ew) {
                const int t = eh * 5 + ew;
                const short8 ahi = *(const short8*)(Abase + t * 2048);
                const short8 alo = *(const short8*)(Abase + t * 2048 + 512);
#pragma unroll
                for (int g = 0; g < 4; ++g) {
                    const int r = wid * 4 + g;
                    const short8 bf = *(const short8*)(stag + ((r + eh) * 20 + ew) * 32 + lane_off);
                    acc[g] = __builtin_amdgcn_mfma_f32_16x16x32_bf16(ahi, bf, acc[g], 0, 0, 0);
                    acc[g] = __builtin_amdgcn_mfma_f32_16x16x32_bf16(alo, bf, acc[g], 0, 0, 0);
                }
            }
        }
    }
    // epilogue: D row m = q*4+reg, col = n; add gated bias, store
    const int gj = j0 + n;
    const int jc = gj < 2 ? gj : (gj > 125 ? gj - 123 : 2);
#pragma unroll
    for (int g = 0; g < 4; ++g) {
        const int gi = i0 + wid * 4 + g;
        const int ic = gi < 2 ? gi : (gi > 125 ? gi - 123 : 2);
        const float* bgp = &bg[(ic * 5 + jc) * 9];
#pragma unroll
        for (int ridx = 0; ridx < 4; ++ridx) {
            const int m = q * 4 + ridx;
            if (m < NK)
                wt[(((size_t)b * NK + m) * HW + gi) * HW + gj] = acc[g][ridx] + bgp[m];
        }
    }
}

// ---------- kernel 7: softmax over 9 taps + dynamic blur ----------
// grid (64 tiles, 8b*4cgrp): 16 channels per block -> 8 blocks/CU
__global__ __launch_bounds__(256) void out_kernel(const float* __restrict__ x,
                                                  const float* __restrict__ wt,
                                                  const float* __restrict__ tmp,
                                                  float* __restrict__ out) {
    __shared__ float lt[16];
    __shared__ float lx[18 * 18];
    const int b = blockIdx.y >> 2, cgrp = blockIdx.y & 3;
    const int ty = blockIdx.x >> 3, tx = blockIdx.x & 7;
    const int i0 = ty * 16, j0 = tx * 16;
    const int ti = threadIdx.x >> 4, tj = threadIdx.x & 15;
    const int i = i0 + ti, j = j0 + tj;

    if (threadIdx.x < 16) lt[threadIdx.x] = tmp[cgrp * 16 + threadIdx.x];

    float w[NK];
#pragma unroll
    for (int k = 0; k < NK; ++k)
        w[k] = wt[(((size_t)b * NK + k) * HW + i) * HW + j];

    for (int cc = 0; cc < 16; ++cc) {
        const int c = cgrp * 16 + cc;
        __syncthreads();
        for (int idx = threadIdx.x; idx < 18 * 18; idx += 256) {
            const int li = idx / 18, lj = idx - li * 18;
            int gi = i0 + li - 1, gj = j0 + lj - 1;
            gi = gi < 0 ? -gi : (gi > HW - 1 ? 2 * (HW - 1) - gi : gi);
            gj = gj < 0 ? -gj : (gj > HW - 1 ? 2 * (HW - 1) - gj : gj);
            lx[idx] = x[(((size_t)b * C + c) * HW + gi) * HW + gj];
        }
        __syncthreads();
        const float t = lt[cc];
        float l[NK], m = -1e30f;
#pragma unroll
        for (int k = 0; k < NK; ++k) {
            l[k] = w[k] * t;
            m = fmaxf(m, l[k]);
        }
        float e[NK], s = 0.f;
#pragma unroll
        for (int k = 0; k < NK; ++k) {
            e[k] = __expf(l[k] - m);
            s += e[k];
        }
        float o = 0.f;
#pragma unroll
        for (int k = 0; k < NK; ++k) {
            const int dh = k / 3, dw = k - dh * 3;
            o += e[k] * lx[(ti + dh) * 18 + (tj + dw)];
        }
        out[(((size_t)b * C + c) * HW + i) * HW + j] = o / s;
    }
}

extern "C" void kernel_launch(void* const* d_in, const int* in_sizes, int n_in,
                              void* d_out, int out_size, void* d_ws, size_t ws_size,
                              hipStream_t stream) {
    const float* x   = (const float*)d_in[0];
    const float* w1  = (const float*)d_in[1];
    const float* b1  = (const float*)d_in[2];
    const float* w2  = (const float*)d_in[3];
    const float* tc1 = (const float*)d_in[4];
    const float* tc2 = (const float*)d_in[5];
    float* out = (float*)d_out;

    // workspace layout (bytes)
    char* ws = (char*)d_ws;
    float* part  = (float*)(ws + 0);           // 256 fl       -> 1024 B
    float* tmp   = (float*)(ws + 1024);        // 64 fl
    float* betaG = (float*)(ws + 2048);        // 225 fl
    unsigned short* Abuf = (unsigned short*)(ws + 4096);       // 51200 ush = 102400 B
    float* wt    = (float*)(ws + 106496);      // 1179648 fl = 4718592 B
    unsigned short* xT = (unsigned short*)(ws + 4825088);      // 8388608 ush = 16777216 B
    // total ~21.6 MB

    transpose_kernel<<<dim3(HW, B), 256, 0, stream>>>(x, xT);
    xcon_part_kernel<<<256, 256, 0, stream>>>(x, part);
    tmp_kernel<<<1, 64, 0, stream>>>(part, tc1, tc2, tmp);
    weffA_kernel<<<100, 256, 0, stream>>>(w1, w2, Abuf);
    beta_kernel<<<1, 256, 0, stream>>>(b1, w2, betaG);
    conv_mfma_kernel<<<dim3(64, B), 256, 0, stream>>>(xT, Abuf, betaG, wt);
    out_kernel<<<dim3(64, B * 4), 256, 0, stream>>>(x, wt, tmp, out);
}

// Round 3
// 163.636 us; speedup vs baseline: 1.9585x; 1.0628x over previous
//
#include <hip/hip_runtime.h>
#include <hip/hip_bf16.h>
#include <cstddef>

// x: (8,64,128,128) fp32 | w1:(64,64,1,1) | b1:(64,) | w2:(9,64,5,5)
// tc1:(16,64,1,1) | tc2:(64,16,1,1) | out:(8,64,128,128) fp32
//
// wt = conv5x5(conv1x1(x)+b1) as GEMM on MFMA (A = Weff hi/lo bf16 split,
// B = bf16 x staged in LDS), then softmax over 9 taps * tmp[c] and 3x3
// reflect-pad blur -- all in ONE kernel per 16x16 pixel tile (wt never
// touches HBM; blur reuses the same LDS stag tile).

#define B 8
#define C 64
#define HW 128
#define NK 9
#define NT 25
#define LOG2E 1.4426950408889634f

typedef __attribute__((ext_vector_type(8))) short short8;    // 8 bf16
typedef __attribute__((ext_vector_type(4))) float float4v;   // 4 fp32 acc
typedef __attribute__((ext_vector_type(4))) unsigned int uint4v;

__device__ __forceinline__ unsigned short f2bf(float f) {
    unsigned int u = __float_as_uint(f);
    unsigned int r = u + 0x7FFF + ((u >> 16) & 1);   // RNE
    return (unsigned short)(r >> 16);
}
__device__ __forceinline__ float fast_exp2(float x) {   // v_exp_f32: D = 2^S0
    float r;
    asm("v_exp_f32 %0, %1" : "=v"(r) : "v"(x));
    return r;
}
__device__ __forceinline__ float fast_rcp(float x) {    // ~1 ulp reciprocal
    float r;
    asm("v_rcp_f32 %0, %1" : "=v"(r) : "v"(x));
    return r;
}

// ---------- kernel 1: x (b,c,h,w) fp32 -> xT (b,h,w,c) bf16, + channel sums ----------
__global__ __launch_bounds__(256) void transpose_kernel(const float* __restrict__ x,
                                                        unsigned short* __restrict__ xT,
                                                        float* __restrict__ part) {
    __shared__ float tile[64 * 129];
    const int gi = blockIdx.x, b = blockIdx.y;
    const int tid = threadIdx.x;
    for (int it = 0; it < 8; ++it) {
        const int idx = it * 256 + tid;
        const int cidx = idx >> 5, f4 = idx & 31;
        float4 v = *(const float4*)(x + (((size_t)(b * C + cidx)) * HW + gi) * HW + f4 * 4);
        tile[cidx * 129 + f4 * 4 + 0] = v.x;
        tile[cidx * 129 + f4 * 4 + 1] = v.y;
        tile[cidx * 129 + f4 * 4 + 2] = v.z;
        tile[cidx * 129 + f4 * 4 + 3] = v.w;
    }
    __syncthreads();
    for (int it = 0; it < 4; ++it) {
        const int idx = it * 256 + tid;
        const int gj = idx >> 3, c8 = idx & 7;
        unsigned int p[4];
#pragma unroll
        for (int s = 0; s < 4; ++s) {
            unsigned int lo = f2bf(tile[(c8 * 8 + 2 * s) * 129 + gj]);
            unsigned int hi = f2bf(tile[(c8 * 8 + 2 * s + 1) * 129 + gj]);
            p[s] = lo | (hi << 16);
        }
        uint4v outv = {p[0], p[1], p[2], p[3]};
        *(uint4v*)(xT + (((size_t)b * (HW * HW) + gi * HW + gj) * C + c8 * 8)) = outv;
    }
    // fused xcon partial: per-channel row sum -> atomic accumulate
    if (tid < 64) {
        float s = 0.f;
        for (int g = 0; g < 128; ++g) s += tile[tid * 129 + g];
        atomicAdd(part + tid, s);
    }
}

// ---------- kernel 2: Abuf (MFMA A-fragments, hi/lo bf16) + betaG ----------
__global__ __launch_bounds__(256) void prep_kernel(const float* __restrict__ w1,
                                                   const float* __restrict__ b1,
                                                   const float* __restrict__ w2,
                                                   unsigned short* __restrict__ Abuf,
                                                   float* __restrict__ betaG) {
    if (blockIdx.x < 100) {
        const int idx = blockIdx.x * 256 + threadIdx.x;   // 25600 slots
        const int chunk = idx >> 9;            // t*2+ch
        const int rem = idx & 511;             // (quad*16+m)*8+j
        const int quad = rem >> 7;
        const int m = (rem >> 3) & 15;
        const int j = rem & 7;
        const int t = chunk >> 1, ch = chunk & 1;
        const int c = ch * 32 + quad * 8 + j;
        unsigned short hi = 0, lo = 0;
        if (m < NK) {
            float s = 0.f;
            for (int cc = 0; cc < C; ++cc)
                s += w2[(m * C + cc) * NT + t] * w1[cc * C + c];
            hi = f2bf(s);
            float fhi = __uint_as_float(((unsigned int)hi) << 16);
            lo = f2bf(s - fhi);
        }
        Abuf[chunk * 1024 + rem] = hi;
        Abuf[chunk * 1024 + 512 + rem] = lo;
    } else {
        __shared__ float beta_s[NT * NK];
        const int t0 = threadIdx.x;
        if (t0 < NT * NK) {
            const int t = t0 / NK, k = t0 - t * NK;
            float s = 0.f;
            for (int cc = 0; cc < C; ++cc)
                s += w2[(k * C + cc) * NT + t] * b1[cc];
            beta_s[t0] = s;
        }
        __syncthreads();
        if (t0 < 225) {   // (ic,jc,k) border classes
            const int ic = t0 / 45, jc = (t0 / 9) % 5, k = t0 % 9;
            float s = 0.f;
            for (int eh = 0; eh < 5; ++eh) {
                bool rok = (ic == 0) ? (eh >= 2) : (ic == 1) ? (eh >= 1)
                          : (ic == 3) ? (eh <= 3) : (ic == 4) ? (eh <= 2) : true;
                if (!rok) continue;
                for (int ew = 0; ew < 5; ++ew) {
                    bool cok = (jc == 0) ? (ew >= 2) : (jc == 1) ? (ew >= 1)
                              : (jc == 3) ? (ew <= 3) : (jc == 4) ? (ew <= 2) : true;
                    if (cok) s += beta_s[(eh * 5 + ew) * NK + k];
                }
            }
            betaG[t0] = s;
        }
    }
}

// ---------- kernel 3: fused conv(MFMA) + consensus + softmax + blur ----------
// block 256 = 4 waves, one 16x16 pixel tile. LDS: stag[2][400][40] bf16
// (stride 40 = bank-conflict-free for b128), lt[64]. ONE barrier.
__global__ __launch_bounds__(256) void fused_kernel(const unsigned short* __restrict__ xT,
                                                    const unsigned short* __restrict__ Abuf,
                                                    const float* __restrict__ betaG,
                                                    const float* __restrict__ part,
                                                    const float* __restrict__ tc1,
                                                    const float* __restrict__ tc2,
                                                    float* __restrict__ out) {
    __shared__ unsigned short stag[2 * 400 * 40];   // 64000 B
    __shared__ float lt[C];                         // tmp[c] * log2(e)

    const int b = blockIdx.y;
    const int ty = blockIdx.x >> 3, tx = blockIdx.x & 7;
    const int i0 = ty * 16, j0 = tx * 16;
    const int tid = threadIdx.x;
    const int lane = tid & 63, wid = tid >> 6;
    const int n = lane & 15, q = lane >> 4;

    // ---- stage 20x20 halo x 64 ch bf16 (zero pad = conv's y zero-pad) ----
    for (int idx = tid; idx < 3200; idx += 256) {
        const int pix = idx >> 3, g8 = idx & 7;
        const int li = pix / 20, lj = pix - li * 20;
        const int gi = i0 + li - 2, gj = j0 + lj - 2;
        uint4v v = {0u, 0u, 0u, 0u};
        if (gi >= 0 && gi < HW && gj >= 0 && gj < HW)
            v = *(const uint4v*)(xT + (((size_t)b * (HW * HW) + gi * HW + gj) * C + g8 * 8));
        *(uint4v*)(stag + (g8 >> 2) * 16000 + pix * 40 + (g8 & 3) * 8) = v;
    }

    // ---- wave0: consensus lt[c] = relu(tc2 @ relu(tc1 @ xcon)) * log2e ----
    if (wid == 0) {
        float xcv = part[lane] * (1.f / (B * HW * HW));
        float h = 0.f;
        for (int c = 0; c < C; ++c) {
            float xcc = __shfl(xcv, c);
            if (lane < 16) h += tc1[lane * C + c] * xcc;
        }
        h = fmaxf(h, 0.f);
        float ltv = 0.f;
#pragma unroll
        for (int o = 0; o < 16; ++o) {
            float ho = __shfl(h, o);
            ltv += tc2[lane * 16 + o] * ho;
        }
        lt[lane] = fmaxf(ltv, 0.f) * LOG2E;
    }

    // ---- per-thread pixel, gated bias (global reads overlap staging) ----
    const int ti = tid >> 4, tj = tid & 15;
    const int gi = i0 + ti, gj = j0 + tj;
    const int ic = gi < 2 ? gi : (gi > 125 ? gi - 123 : 2);
    const int jc = gj < 2 ? gj : (gj > 125 ? gj - 123 : 2);
    float bgv[NK];
#pragma unroll
    for (int k = 0; k < NK; ++k) bgv[k] = betaG[(ic * 5 + jc) * NK + k];

    __syncthreads();   // stag + lt ready

    // ---- MFMA conv: 2 halves x 25 taps x 4 subtiles x (hi+lo) ----
    float4v acc[4];
    const float4v zero4 = {0.f, 0.f, 0.f, 0.f};
#pragma unroll
    for (int g = 0; g < 4; ++g) acc[g] = zero4;

    for (int half = 0; half < 2; ++half) {
        const unsigned short* Ab = Abuf + half * 1024 + lane * 8;
        const unsigned short* sb = stag + half * 16000 + q * 8;
#pragma unroll
        for (int eh = 0; eh < 5; ++eh) {
#pragma unroll
            for (int ew = 0; ew < 5; ++ew) {
                const int t = eh * 5 + ew;
                const short8 ahi = *(const short8*)(Ab + t * 2048);
                const short8 alo = *(const short8*)(Ab + t * 2048 + 512);
#pragma unroll
                for (int g = 0; g < 4; ++g) {
                    const int r = wid * 4 + g;
                    const short8 bf = *(const short8*)(sb + ((r + eh) * 20 + ew + n) * 40);
                    acc[g] = __builtin_amdgcn_mfma_f32_16x16x32_bf16(ahi, bf, acc[g], 0, 0, 0);
                    acc[g] = __builtin_amdgcn_mfma_f32_16x16x32_bf16(alo, bf, acc[g], 0, 0, 0);
                }
            }
        }
    }

    // ---- intra-wave exchange: lane gets all 9 taps of its own pixel ----
    // writer: lane (q,n) holds D[m=q*4+r][n] of subtile g (row wid*4+g)
    // reader: lane l owns pixel (row wid*4+(l>>4), col l&15)
    float w[NK];
#pragma unroll
    for (int k = 0; k < NK; ++k) {
        const int src = (k >> 2) * 16 + n;
        const int rr = k & 3;
        float v0 = __shfl(acc[0][rr], src);
        float v1 = __shfl(acc[1][rr], src);
        float v2 = __shfl(acc[2][rr], src);
        float v3 = __shfl(acc[3][rr], src);
        const int g = lane >> 4;
        float v = (g == 0) ? v0 : (g == 1) ? v1 : (g == 2) ? v2 : v3;
        w[k] = v + bgv[k];
    }

    // ---- softmax prep: d[k] = w[k]-wmax (channel-independent since t>=0) ----
    float wmax = w[0];
#pragma unroll
    for (int k = 1; k < NK; ++k) wmax = fmaxf(wmax, w[k]);
    float d[NK];
#pragma unroll
    for (int k = 0; k < NK; ++k) d[k] = w[k] - wmax;

    // ---- blur tap offsets with reflect padding (always inside stag halo) ----
    int rr0 = gi - 1; rr0 = rr0 < 0 ? 1 : rr0;
    int rr2 = gi + 1; rr2 = rr2 > 127 ? 126 : rr2;
    int cc0 = gj - 1; cc0 = cc0 < 0 ? 1 : cc0;
    int cc2 = gj + 1; cc2 = cc2 > 127 ? 126 : cc2;
    const int R[3] = {rr0 - i0 + 2, gi - i0 + 2, rr2 - i0 + 2};
    const int Cc[3] = {cc0 - j0 + 2, gj - j0 + 2, cc2 - j0 + 2};
    int off9[NK];
#pragma unroll
    for (int kh = 0; kh < 3; ++kh)
#pragma unroll
        for (int kw = 0; kw < 3; ++kw)
            off9[kh * 3 + kw] = (R[kh] * 20 + Cc[kw]) * 40;

    // ---- epilogue: 8 channel-octets; 9 b128 reads each; 2 ch per uint ----
    float* outp = out + ((size_t)b * C * (HW * HW) + gi * HW + gj);
    for (int g8 = 0; g8 < 8; ++g8) {
        const unsigned short* sb2 = stag + (g8 >> 2) * 16000 + (g8 & 3) * 8;
        uint4v xs[NK];
#pragma unroll
        for (int k = 0; k < NK; ++k) xs[k] = *(const uint4v*)(sb2 + off9[k]);
#pragma unroll
        for (int j = 0; j < 4; ++j) {
            const int c0 = g8 * 8 + j * 2;
            {
                const float t = lt[c0];
                float s = 0.f, o = 0.f;
#pragma unroll
                for (int k = 0; k < NK; ++k) {
                    const float e = fast_exp2(d[k] * t);
                    const float xv = __uint_as_float(xs[k][j] << 16);
                    s += e;
                    o = fmaf(e, xv, o);
                }
                outp[(size_t)c0 * (HW * HW)] = o * fast_rcp(s);
            }
            {
                const float t = lt[c0 + 1];
                float s = 0.f, o = 0.f;
#pragma unroll
                for (int k = 0; k < NK; ++k) {
                    const float e = fast_exp2(d[k] * t);
                    const float xv = __uint_as_float(xs[k][j] & 0xffff0000u);
                    s += e;
                    o = fmaf(e, xv, o);
                }
                outp[(size_t)(c0 + 1) * (HW * HW)] = o * fast_rcp(s);
            }
        }
    }
}

extern "C" void kernel_launch(void* const* d_in, const int* in_sizes, int n_in,
                              void* d_out, int out_size, void* d_ws, size_t ws_size,
                              hipStream_t stream) {
    const float* x   = (const float*)d_in[0];
    const float* w1  = (const float*)d_in[1];
    const float* b1  = (const float*)d_in[2];
    const float* w2  = (const float*)d_in[3];
    const float* tc1 = (const float*)d_in[4];
    const float* tc2 = (const float*)d_in[5];
    float* out = (float*)d_out;

    // workspace layout (bytes)
    char* ws = (char*)d_ws;
    float* part  = (float*)(ws + 0);                       // 64 fl
    unsigned short* Abuf = (unsigned short*)(ws + 1024);   // 51200 ush = 102400 B
    float* betaG = (float*)(ws + 103424);                  // 225 fl
    unsigned short* xT = (unsigned short*)(ws + 104448);   // 8.4M ush = 16.8 MB

    hipMemsetAsync(part, 0, 64 * sizeof(float), stream);
    transpose_kernel<<<dim3(HW, B), 256, 0, stream>>>(x, xT, part);
    prep_kernel<<<101, 256, 0, stream>>>(w1, b1, w2, Abuf, betaG);
    fused_kernel<<<dim3(64, B), 256, 0, stream>>>(xT, Abuf, betaG, part, tc1, tc2, out);
}